// Round 3
// baseline (463.519 us; speedup 1.0000x reference)
//
#include <hip/hip_runtime.h>
#include <stdint.h>

// Problem constants (fixed by setup_inputs)
#define B_ 64
#define C_ 256
#define H_ 56
#define W_ 56
#define HM 50              // H - (BLOCK_SIZE-1)
#define WM 50
#define NPLANES (B_ * C_)          // 16384
#define PLANE_IN (HM * WM)         // 2500
#define PLANE_OUT (H_ * W_)        // 3136
#define NTOT (NPLANES * PLANE_OUT) // 51,380,224
#define N4 (NTOT / 4)              // 12,845,056 float4s

#define PPB 8                      // planes per dilate block
#define DGRID (NPLANES / PPB)      // 2048 blocks -> 8 blocks/CU, fully resident

typedef float f4 __attribute__((ext_vector_type(4)));

// Persistent dilate: 2048 blocks x 8 planes. Whole grid is resident
// (8 blk/CU x 4 waves = 32 waves/CU), so there is no workgroup re-dispatch;
// the 16384-tiny-block launch overhead of the previous version is gone.
// hdil is double-buffered so only ONE barrier per plane is needed:
// plane k writes hdil[k&1], barrier, wave 0 reads hdil[k&1] while waves 1-3
// run ahead building plane k+1 in hdil[(k+1)&1]. Plane k+2 cannot touch
// hdil[k&1] until barrier k+1, which orders wave 0's reads first. Race-free.
// [R1 lesson: NO single-address global atomics — 16384 of them cost +126 us.]
__global__ __launch_bounds__(256) void dilate_kernel(
        const float* __restrict__ u,
        const float* __restrict__ gamma,
        unsigned long long* __restrict__ mask_out,   // [NPLANES * H_]
        unsigned int* __restrict__ counts) {         // [NPLANES]
    __shared__ unsigned long long hdil[2][HM];   // 800 B

    const int tid   = threadIdx.x;
    const int wave  = tid >> 6;
    const int lane  = tid & 63;
    const float g   = gamma[0];

    #pragma unroll 1
    for (int k = 0; k < PPB; ++k) {
        const int plane = blockIdx.x * PPB + k;     // contiguous u streaming
        const float* up = u + (size_t)plane * PLANE_IN;
        unsigned long long* hd = hdil[k & 1];

        // Rows r = wave + 4*i. Lanes 0..49 load row floats (contiguous 200 B),
        // ballot packs the predicate into a 64-bit row mask.
        #pragma unroll
        for (int i = 0; i < 13; ++i) {
            int r = wave + 4 * i;
            float v = 1e30f;                    // predicate false for idle lanes
            if (r < HM && lane < WM) v = up[r * WM + lane];
            unsigned long long bits = __ballot(v < g);
            // horizontal dilation: OR of shifts 0..6 via log-step smear
            unsigned long long h = bits | (bits << 1);
            h |= h << 2;
            h |= h << 3;
            if (lane == 0 && r < HM) hd[r] = h;
        }
        __syncthreads();

        // Vertical dilation: output row t covers seed rows [t-6, t] ∩ [0, HM).
        unsigned int zcnt = 0;
        if (tid < H_) {
            int r0 = tid - 6; if (r0 < 0) r0 = 0;
            int r1 = tid;     if (r1 > HM - 1) r1 = HM - 1;
            unsigned long long v = 0ull;
            for (int r = r0; r <= r1; ++r) v |= hd[r];
            unsigned long long keep = (~v) & ((1ULL << W_) - 1ULL);
            mask_out[(size_t)plane * H_ + tid] = keep;
            zcnt = (unsigned int)__popcll(keep);
        }
        // Threads 0..55 are all in wave 0: shuffle-reduce, one store per plane.
        if (wave == 0) {
            #pragma unroll
            for (int off = 32; off > 0; off >>= 1)
                zcnt += __shfl_down(zcnt, off, 64);
            if (lane == 0) counts[plane] = zcnt;
        }
    }
}

// Grid-stride elementwise: out = x * scale * keep_bit.
// Reduce kernel is FOLDED IN: every block redundantly sums the 16384
// per-plane counts (64 KB, L2/L3-resident; ~268 MB aggregate at L2 BW
// ≈ 8 us spread over 4096 parallel blocks) — removes the serial 1-CU
// reduce dispatch + a launch gap. Integer sum is order-independent, so
// scale is bit-identical to the old reduce kernel's result.
// ~63% of pixels are dropped (gamma=0.02, 7x7 dilation -> keep = .98^49).
// Dropped runs are >=7 wide, so many full 64B cachelines of x are never
// needed — predicate the x load on (bits != 0) so masked-off quads issue no
// memory request. Nontemporal hints: x and out are streamed exactly once;
// keep the 7.3 MB mask + 64 KB counts L2-resident instead.
__global__ __launch_bounds__(256) void apply_kernel(
        const float* __restrict__ x,
        const unsigned long long* __restrict__ mask,
        const unsigned int* __restrict__ counts,
        float* __restrict__ out) {
    __shared__ unsigned int sdata[4];
    __shared__ float s_scale;
    const int tid  = threadIdx.x;
    const int wave = tid >> 6;
    const int lane = tid & 63;

    // Per-block redundant count reduction -> scale.
    unsigned int sum = 0;
    const uint4* c4 = (const uint4*)counts;            // 4096 uint4
    for (int i = tid; i < NPLANES / 4; i += 256) {
        uint4 v = c4[i];
        sum += v.x + v.y + v.z + v.w;
    }
    #pragma unroll
    for (int off = 32; off > 0; off >>= 1)
        sum += __shfl_down(sum, off, 64);
    if (lane == 0) sdata[wave] = sum;
    __syncthreads();
    if (tid == 0)
        s_scale = (float)NTOT /
                  (float)(sdata[0] + sdata[1] + sdata[2] + sdata[3]);
    __syncthreads();
    const float scale = s_scale;

    const f4* xp = (const f4*)x;
    f4*       op = (f4*)out;
    const int stride = gridDim.x * 256;

    for (int idx4 = blockIdx.x * 256 + threadIdx.x; idx4 < N4; idx4 += stride) {
        int word = idx4 / 14;            // = plane*56 + h  (W_/4 == 14)
        int w4   = idx4 - word * 14;
        unsigned int bits = (unsigned int)(mask[word] >> (w4 * 4)) & 0xFu;
        f4 o = {0.0f, 0.0f, 0.0f, 0.0f};
        if (bits) {                      // skip x fetch for fully-dropped quads
            f4 v = __builtin_nontemporal_load(&xp[idx4]);
            o.x = (bits & 1u) ? v.x * scale : 0.0f;
            o.y = (bits & 2u) ? v.y * scale : 0.0f;
            o.z = (bits & 4u) ? v.z * scale : 0.0f;
            o.w = (bits & 8u) ? v.w * scale : 0.0f;
        }
        __builtin_nontemporal_store(o, &op[idx4]);
    }
}

extern "C" void kernel_launch(void* const* d_in, const int* in_sizes, int n_in,
                              void* d_out, int out_size, void* d_ws, size_t ws_size,
                              hipStream_t stream) {
    const float* x     = (const float*)d_in[0];
    const float* u     = (const float*)d_in[1];
    const float* gamma = (const float*)d_in[2];
    float* out = (float*)d_out;

    // Workspace: [0,1024) unused; [1024, 1024+64KB) per-plane counts;
    //            [66560, +7.34MB) bit-packed keep mask.
    unsigned int* counts = (unsigned int*)((char*)d_ws + 1024);
    unsigned long long* mask =
        (unsigned long long*)((char*)d_ws + 1024 + NPLANES * sizeof(unsigned int));

    dilate_kernel<<<DGRID, 256, 0, stream>>>(u, gamma, mask, counts);
    apply_kernel<<<4096, 256, 0, stream>>>(x, mask, counts, out);
}